// Round 4
// baseline (2216.756 us; speedup 1.0000x reference)
//
#include <hip/hip_runtime.h>
#include <cstdint>
#include <cstddef>

// Problem constants (fixed by reference)
#define BB 32
#define NN 8192
#define DIN 64
#define DOUT 128
#define NR 4
#define BN_EPS 1e-5f

#define SEGS 4  // point segments per (b, ring) bucket in compute kernel

typedef float nfloat4 __attribute__((ext_vector_type(4)));  // clang-native float4

// Workspace layout (~2.2 MB):
//   [0, 512)       int  counts[B*NR]        (memset 0 each launch)
//   [512, 66048)   uint smax_keys[B*NR*128] (memset 0 == -NaN key, acts as -inf)
//   [66560, ...)   u16  buckets[B*NR*NN]    (2 MB, no init needed)
// xt (point-major transpose of x, 64 MB) lives in the FIRST HALF of d_out:
// k_compute consumes it before k_out overwrites d_out (k_out reads only
// keys/ring, never xt, so the aliasing is stream-order safe).
#define WS_KEYS_OFF 512
#define WS_BUCKETS_OFF 66560

// ---------------------------------------------------------------------------
// K1: bucket points by (batch, ring). Wave-aggregated atomics.
__global__ void k_bucket(const int* __restrict__ ring, int* __restrict__ counts,
                         unsigned short* __restrict__ buckets) {
  const int b = blockIdx.y;
  const int n0 = blockIdx.x * 1024;
  const int lane = threadIdx.x & 63;
#pragma unroll
  for (int k = 0; k < 4; ++k) {
    const int n = n0 + k * 256 + (int)threadIdx.x;
    const int r = ring[b * NN + n];
    unsigned long long mym = 0ull;
#pragma unroll
    for (int rr = 0; rr < NR; ++rr) {
      unsigned long long mr = __ballot(r == rr);
      if (r == rr) mym = mr;
    }
    const int leader = __ffsll((unsigned long long)mym) - 1;
    const int cnt = __popcll(mym);
    const int pos_in = __popcll(mym & ((1ull << lane) - 1ull));
    int base = 0;
    if (lane == leader) base = atomicAdd(&counts[b * NR + r], cnt);
    base = __shfl(base, leader, 64);
    buckets[(b * NR + r) * NN + base + pos_in] = (unsigned short)n;
  }
}

// ---------------------------------------------------------------------------
// K2: transpose x[b][64][N] -> xt[b][N][64] via a 64x256 LDS tile.
// Both global sides coalesced; LDS column reads are conflict-free (lanes hit
// consecutive banks).
__global__ void __launch_bounds__(256) k_transpose(const float* __restrict__ x,
                                                   float* __restrict__ xt) {
  const int b = blockIdx.y;
  const int n0 = blockIdx.x * 256;
  __shared__ float tile[DIN * 256];
  const int wave = threadIdx.x >> 6;
  const int lane = threadIdx.x & 63;
#pragma unroll
  for (int d = wave; d < DIN; d += 4) {
    const float4 v =
        *(const float4*)&x[((size_t)b * DIN + d) * NN + n0 + lane * 4];
    *(float4*)&tile[d * 256 + lane * 4] = v;
  }
  __syncthreads();
  const int p = (int)threadIdx.x;
  float* dst = &xt[((size_t)b * NN + n0 + p) * DIN];
#pragma unroll
  for (int j = 0; j < 16; ++j) {
    float4 v;
    v.x = tile[(4 * j + 0) * 256 + p];
    v.y = tile[(4 * j + 1) * 256 + p];
    v.z = tile[(4 * j + 2) * 256 + p];
    v.w = tile[(4 * j + 3) * 256 + p];
    *(float4*)&dst[4 * j] = v;
  }
}

// ---------------------------------------------------------------------------
// K3: per-(b, ring, segment) block computes running max of raw dots for ALL
// 128 channels: wave w owns channels [32w, 32w+32). All 4 waves iterate the
// SAME points each iteration (different channels) -> x fetched once, waves
// 1-3 hit L1/L2. Point gather is 16 contiguous float4 (4 fully-used lines).
__global__ void __launch_bounds__(256) k_compute(
    const float* __restrict__ xt, const float* __restrict__ W,
    const int* __restrict__ counts, const unsigned short* __restrict__ buckets,
    unsigned int* __restrict__ smax_keys) {
  const int seg = blockIdx.x;
  const int r = blockIdx.y;
  const int b = blockIdx.z;
  const int wave = threadIdx.x >> 6;
  const int lane = threadIdx.x & 63;
  const int count = counts[b * NR + r];
  const unsigned short* bk = buckets + (size_t)(b * NR + r) * NN;
  const float* xb = xt + (size_t)b * NN * DIN;
  const float* Wr = W + (size_t)(r * DOUT + wave * 32) * DIN;

  float maxacc[32];
#pragma unroll
  for (int i = 0; i < 32; ++i) maxacc[i] = -INFINITY;

  for (int i = seg * 64 + lane; i < count; i += SEGS * 64) {
    const int n = bk[i];
    const float* xp = xb + (size_t)n * DIN;
    float xr[DIN];
#pragma unroll
    for (int j = 0; j < 16; ++j) {
      const float4 v = *(const float4*)&xp[4 * j];
      xr[4 * j + 0] = v.x;
      xr[4 * j + 1] = v.y;
      xr[4 * j + 2] = v.z;
      xr[4 * j + 3] = v.w;
    }
#pragma unroll
    for (int oo = 0; oo < 32; ++oo) {
      const float* w = Wr + oo * DIN;
      float a0 = 0.f, a1 = 0.f;  // two partial sums for FMA-latency ILP
#pragma unroll
      for (int d = 0; d < DIN; d += 2) {
        a0 = fmaf(w[d], xr[d], a0);
        a1 = fmaf(w[d + 1], xr[d + 1], a1);
      }
      maxacc[oo] = fmaxf(maxacc[oo], a0 + a1);
    }
  }

  // 64-lane butterfly max per channel; lane oo keeps channel oo's result.
  float keep = 0.f;
#pragma unroll
  for (int oo = 0; oo < 32; ++oo) {
    float v = maxacc[oo];
#pragma unroll
    for (int k = 32; k >= 1; k >>= 1) v = fmaxf(v, __shfl_xor(v, k, 64));
    if (lane == oo) keep = v;
  }
  if (lane < 32) {
    // order-preserving float->uint key so atomicMax(uint) == float max
    const unsigned int u = __float_as_uint(keep);
    const unsigned int key = (u & 0x80000000u) ? ~u : (u | 0x80000000u);
    atomicMax(&smax_keys[(size_t)(b * NR + r) * DOUT + wave * 32 + lane], key);
  }
}

// ---------------------------------------------------------------------------
// K4: finalize affine on the 16K maxima, then broadcast to output:
// out[b][o][n] = ymax[b][ring[b,n]][o]. Nontemporal float4 stores along n.
// LDS table [oo][r] so the 4 ring values sit in 4 different banks.
__global__ void k_out(const float* __restrict__ bias, const float* __restrict__ gamma,
                      const float* __restrict__ beta, const float* __restrict__ mean,
                      const float* __restrict__ var, const int* __restrict__ ring,
                      const unsigned int* __restrict__ smax_keys,
                      float* __restrict__ out) {
  const int b = blockIdx.z;
  const int og = blockIdx.y;  // 32-channel group
  const int n0 = blockIdx.x * 1024;

  __shared__ float ymax[32 * NR];  // [oo][r]
  if (threadIdx.x < 32 * NR) {
    const int oo = (int)threadIdx.x >> 2;
    const int r = (int)threadIdx.x & 3;
    const int o = og * 32 + oo;
    const int t = r * DOUT + o;
    const unsigned int key = smax_keys[(size_t)b * NR * DOUT + t];
    const unsigned int u = (key & 0x80000000u) ? (key ^ 0x80000000u) : ~key;
    const float raw = __uint_as_float(u);
    const float sc = gamma[t] * rsqrtf(var[t] + BN_EPS);
    ymax[oo * NR + r] = (raw + bias[t] - mean[t]) * sc + beta[t];
  }
  __syncthreads();

  const int n = n0 + (int)threadIdx.x * 4;
  const int4 rg = *(const int4*)&ring[(size_t)b * NN + n];
#pragma unroll 8
  for (int oo = 0; oo < 32; ++oo) {
    const int o = og * 32 + oo;
    nfloat4 v;
    v.x = ymax[oo * NR + rg.x];
    v.y = ymax[oo * NR + rg.y];
    v.z = ymax[oo * NR + rg.z];
    v.w = ymax[oo * NR + rg.w];
    __builtin_nontemporal_store(v, (nfloat4*)&out[((size_t)b * DOUT + o) * NN + n]);
  }
}

// ---------------------------------------------------------------------------
extern "C" void kernel_launch(void* const* d_in, const int* in_sizes, int n_in,
                              void* d_out, int out_size, void* d_ws, size_t ws_size,
                              hipStream_t stream) {
  const float* x = (const float*)d_in[0];
  const int* ring = (const int*)d_in[1];
  const float* W = (const float*)d_in[2];
  const float* bias = (const float*)d_in[3];
  const float* gamma = (const float*)d_in[4];
  const float* beta = (const float*)d_in[5];
  const float* mean = (const float*)d_in[6];
  const float* var = (const float*)d_in[7];
  float* out = (float*)d_out;

  char* ws = (char*)d_ws;
  int* counts = (int*)(ws + 0);
  unsigned int* keys = (unsigned int*)(ws + WS_KEYS_OFF);
  unsigned short* buckets = (unsigned short*)(ws + WS_BUCKETS_OFF);
  float* xt = (float*)d_out;  // first 64 MB of d_out; consumed before k_out

  // zero counts + smax keys (key 0 decodes to -NaN, i.e. identity for max)
  (void)hipMemsetAsync(ws, 0, WS_KEYS_OFF + (size_t)BB * NR * DOUT * 4, stream);

  k_bucket<<<dim3(NN / 1024, BB), 256, 0, stream>>>(ring, counts, buckets);
  k_transpose<<<dim3(NN / 256, BB), 256, 0, stream>>>(x, xt);
  k_compute<<<dim3(SEGS, NR, BB), 256, 0, stream>>>(xt, W, counts, buckets, keys);
  k_out<<<dim3(NN / 1024, DOUT / 32, BB), 256, 0, stream>>>(bias, gamma, beta, mean,
                                                            var, ring, keys, out);
}

// Round 5
// 338.357 us; speedup vs baseline: 6.5515x; 6.5515x over previous
//
#include <hip/hip_runtime.h>
#include <cstdint>
#include <cstddef>

// Problem constants (fixed by reference)
#define BB 32
#define NN 8192
#define DIN 64
#define DOUT 128
#define NR 4
#define BN_EPS 1e-5f

#define SEGS 12  // point-stream segments per (b, ring); 2 streams per block

typedef float nfloat4 __attribute__((ext_vector_type(4)));  // clang-native float4

// Workspace layout (~2.2 MB):
//   [0, 512)       int  counts[B*NR]        (memset 0 each launch)
//   [512, 66048)   uint smax_keys[B*NR*128] (memset 0 decodes to -NaN, identity for max)
//   [66560, ...)   u16  buckets[B*NR*NN]    (2 MB, no init needed)
// xt (point-major transpose of x, 64 MB) lives in the FIRST HALF of d_out:
// consumed by k_compute before k_out overwrites d_out.
#define WS_KEYS_OFF 512
#define WS_BUCKETS_OFF 66560

// ---------------------------------------------------------------------------
// K1: bucket points by (batch, ring). Wave-aggregated atomics.
__global__ void k_bucket(const int* __restrict__ ring, int* __restrict__ counts,
                         unsigned short* __restrict__ buckets) {
  const int b = blockIdx.y;
  const int n0 = blockIdx.x * 1024;
  const int lane = threadIdx.x & 63;
#pragma unroll
  for (int k = 0; k < 4; ++k) {
    const int n = n0 + k * 256 + (int)threadIdx.x;
    const int r = ring[b * NN + n];
    unsigned long long mym = 0ull;
#pragma unroll
    for (int rr = 0; rr < NR; ++rr) {
      unsigned long long mr = __ballot(r == rr);
      if (r == rr) mym = mr;
    }
    const int leader = __ffsll((unsigned long long)mym) - 1;
    const int cnt = __popcll(mym);
    const int pos_in = __popcll(mym & ((1ull << lane) - 1ull));
    int base = 0;
    if (lane == leader) base = atomicAdd(&counts[b * NR + r], cnt);
    base = __shfl(base, leader, 64);
    buckets[(b * NR + r) * NN + base + pos_in] = (unsigned short)n;
  }
}

// ---------------------------------------------------------------------------
// K2: transpose x[b][64][N] -> xt[b][N][64] via a 64x256 LDS tile.
__global__ void __launch_bounds__(256) k_transpose(const float* __restrict__ x,
                                                   float* __restrict__ xt) {
  const int b = blockIdx.y;
  const int n0 = blockIdx.x * 256;
  __shared__ float tile[DIN * 256];
  const int wave = threadIdx.x >> 6;
  const int lane = threadIdx.x & 63;
#pragma unroll
  for (int d = wave; d < DIN; d += 4) {
    const float4 v =
        *(const float4*)&x[((size_t)b * DIN + d) * NN + n0 + lane * 4];
    *(float4*)&tile[d * 256 + lane * 4] = v;
  }
  __syncthreads();
  const int p = (int)threadIdx.x;
  float* dst = &xt[((size_t)b * NN + n0 + p) * DIN];
#pragma unroll
  for (int j = 0; j < 16; ++j) {
    float4 v;
    v.x = tile[(4 * j + 0) * 256 + p];
    v.y = tile[(4 * j + 1) * 256 + p];
    v.z = tile[(4 * j + 2) * 256 + p];
    v.w = tile[(4 * j + 3) * 256 + p];
    *(float4*)&dst[4 * j] = v;
  }
}

// ---------------------------------------------------------------------------
// K3: lane = output channel. Per wave: 64 W-row floats in VGPRs (loaded once),
// ONE max accumulator. Each loop iteration handles one whole point whose 64
// x values sit at a WAVE-UNIFORM address (readfirstlane) -> scalar/broadcast
// loads, feeding v_fmac as the SGPR operand. No per-thread arrays => no spill.
// Waves 0,1 = channels 0-63 / 64-127 on point stream A; waves 2,3 same
// channels on stream B. 2*SEGS streams per (b, ring).
__global__ void __launch_bounds__(256) k_compute(
    const float* __restrict__ xt, const float* __restrict__ W,
    const int* __restrict__ counts, const unsigned short* __restrict__ buckets,
    unsigned int* __restrict__ smax_keys) {
  const int seg = blockIdx.x;
  const int r = blockIdx.y;
  const int b = blockIdx.z;
  const int wave = (int)threadIdx.x >> 6;
  const int lane = (int)threadIdx.x & 63;
  const int chan = (wave & 1) * 64 + lane;
  const int stream = seg * 2 + (wave >> 1);
  const int count = counts[b * NR + r];
  const unsigned short* bk = buckets + (size_t)(b * NR + r) * NN;
  const float* xb = xt + (size_t)b * NN * DIN;

  const float* Wrow = W + ((size_t)r * DOUT + chan) * DIN;
  float w[DIN];
#pragma unroll
  for (int dd = 0; dd < DIN; ++dd) w[dd] = Wrow[dd];

  float maxv = -INFINITY;
  for (int i = stream; i < count; i += 2 * SEGS) {
    const int n = __builtin_amdgcn_readfirstlane((int)bk[i]);
    const float* xp = xb + (size_t)n * DIN;
    float a0 = 0.f, a1 = 0.f, a2 = 0.f, a3 = 0.f;
#pragma unroll
    for (int dd = 0; dd < DIN; dd += 4) {
      a0 = fmaf(w[dd + 0], xp[dd + 0], a0);
      a1 = fmaf(w[dd + 1], xp[dd + 1], a1);
      a2 = fmaf(w[dd + 2], xp[dd + 2], a2);
      a3 = fmaf(w[dd + 3], xp[dd + 3], a3);
    }
    maxv = fmaxf(maxv, (a0 + a1) + (a2 + a3));
  }

  // order-preserving float->uint key so atomicMax(uint) == float max
  const unsigned int u = __float_as_uint(maxv);
  const unsigned int key = (u & 0x80000000u) ? ~u : (u | 0x80000000u);
  atomicMax(&smax_keys[(size_t)(b * NR + r) * DOUT + chan], key);
}

// ---------------------------------------------------------------------------
// K4: finalize affine on the 16K maxima, then broadcast to output:
// out[b][o][n] = ymax[b][ring[b,n]][o]. Nontemporal float4 stores along n.
// LDS table [oo][r] so the 4 ring values sit in 4 different banks.
__global__ void k_out(const float* __restrict__ bias, const float* __restrict__ gamma,
                      const float* __restrict__ beta, const float* __restrict__ mean,
                      const float* __restrict__ var, const int* __restrict__ ring,
                      const unsigned int* __restrict__ smax_keys,
                      float* __restrict__ out) {
  const int b = blockIdx.z;
  const int og = blockIdx.y;  // 32-channel group
  const int n0 = blockIdx.x * 1024;

  __shared__ float ymax[32 * NR];  // [oo][r]
  if (threadIdx.x < 32 * NR) {
    const int oo = (int)threadIdx.x >> 2;
    const int r = (int)threadIdx.x & 3;
    const int o = og * 32 + oo;
    const int t = r * DOUT + o;
    const unsigned int key = smax_keys[(size_t)b * NR * DOUT + t];
    const unsigned int u = (key & 0x80000000u) ? (key ^ 0x80000000u) : ~key;
    const float raw = __uint_as_float(u);
    const float sc = gamma[t] * rsqrtf(var[t] + BN_EPS);
    ymax[oo * NR + r] = (raw + bias[t] - mean[t]) * sc + beta[t];
  }
  __syncthreads();

  const int n = n0 + (int)threadIdx.x * 4;
  const int4 rg = *(const int4*)&ring[(size_t)b * NN + n];
#pragma unroll 8
  for (int oo = 0; oo < 32; ++oo) {
    const int o = og * 32 + oo;
    nfloat4 v;
    v.x = ymax[oo * NR + rg.x];
    v.y = ymax[oo * NR + rg.y];
    v.z = ymax[oo * NR + rg.z];
    v.w = ymax[oo * NR + rg.w];
    __builtin_nontemporal_store(v, (nfloat4*)&out[((size_t)b * DOUT + o) * NN + n]);
  }
}

// ---------------------------------------------------------------------------
extern "C" void kernel_launch(void* const* d_in, const int* in_sizes, int n_in,
                              void* d_out, int out_size, void* d_ws, size_t ws_size,
                              hipStream_t stream) {
  const float* x = (const float*)d_in[0];
  const int* ring = (const int*)d_in[1];
  const float* W = (const float*)d_in[2];
  const float* bias = (const float*)d_in[3];
  const float* gamma = (const float*)d_in[4];
  const float* beta = (const float*)d_in[5];
  const float* mean = (const float*)d_in[6];
  const float* var = (const float*)d_in[7];
  float* out = (float*)d_out;

  char* ws = (char*)d_ws;
  int* counts = (int*)(ws + 0);
  unsigned int* keys = (unsigned int*)(ws + WS_KEYS_OFF);
  unsigned short* buckets = (unsigned short*)(ws + WS_BUCKETS_OFF);
  float* xt = (float*)d_out;  // first 64 MB of d_out; consumed before k_out

  // zero counts + smax keys (key 0 decodes to -NaN, i.e. identity for max)
  (void)hipMemsetAsync(ws, 0, WS_KEYS_OFF + (size_t)BB * NR * DOUT * 4, stream);

  k_bucket<<<dim3(NN / 1024, BB), 256, 0, stream>>>(ring, counts, buckets);
  k_transpose<<<dim3(NN / 256, BB), 256, 0, stream>>>(x, xt);
  k_compute<<<dim3(SEGS, NR, BB), 256, 0, stream>>>(xt, W, counts, buckets, keys);
  k_out<<<dim3(NN / 1024, DOUT / 32, BB), 256, 0, stream>>>(bias, gamma, beta, mean,
                                                            var, ring, keys, out);
}

// Round 6
// 259.517 us; speedup vs baseline: 8.5418x; 1.3038x over previous
//
#include <hip/hip_runtime.h>
#include <cstdint>
#include <cstddef>

// Problem constants (fixed by reference)
#define BB 32
#define NN 8192
#define DIN 64
#define DOUT 128
#define NR 4
#define BN_EPS 1e-5f

#define SEGS 16  // point-tile streams per (b, ring)

typedef float nfloat4 __attribute__((ext_vector_type(4)));
typedef float floatx4 __attribute__((ext_vector_type(4)));
typedef short short8 __attribute__((ext_vector_type(8)));
typedef unsigned short ushort8 __attribute__((ext_vector_type(8)));

// Workspace layout (~2.2 MB):
//   [0, 512)       int  counts[B*NR]        (memset 0 each launch)
//   [512, 66048)   uint smax_keys[B*NR*128] (memset 0 decodes to -NaN, identity for max)
//   [66560, ...)   u16  buckets[B*NR*NN]    (2 MB, no init needed)
// xt (point-major BF16 x, 32 MB) lives in the FIRST QUARTER of d_out:
// consumed by k_compute before k_out overwrites d_out.
#define WS_KEYS_OFF 512
#define WS_BUCKETS_OFF 66560

__device__ inline unsigned short f2bf(float f) {  // RNE float->bf16
  const unsigned int u = __float_as_uint(f);
  return (unsigned short)((u + 0x7fffu + ((u >> 16) & 1u)) >> 16);
}

// ---------------------------------------------------------------------------
// K1: bucket points by (batch, ring). Wave-aggregated atomics.
__global__ void k_bucket(const int* __restrict__ ring, int* __restrict__ counts,
                         unsigned short* __restrict__ buckets) {
  const int b = blockIdx.y;
  const int n0 = blockIdx.x * 1024;
  const int lane = threadIdx.x & 63;
#pragma unroll
  for (int k = 0; k < 4; ++k) {
    const int n = n0 + k * 256 + (int)threadIdx.x;
    const int r = ring[b * NN + n];
    unsigned long long mym = 0ull;
#pragma unroll
    for (int rr = 0; rr < NR; ++rr) {
      unsigned long long mr = __ballot(r == rr);
      if (r == rr) mym = mr;
    }
    const int leader = __ffsll((unsigned long long)mym) - 1;
    const int cnt = __popcll(mym);
    const int pos_in = __popcll(mym & ((1ull << lane) - 1ull));
    int base = 0;
    if (lane == leader) base = atomicAdd(&counts[b * NR + r], cnt);
    base = __shfl(base, leader, 64);
    buckets[(b * NR + r) * NN + base + pos_in] = (unsigned short)n;
  }
}

// ---------------------------------------------------------------------------
// K2: transpose+convert x[b][64][N](f32) -> xt[b][N][64](bf16) via LDS tile.
__global__ void __launch_bounds__(256) k_transpose(const float* __restrict__ x,
                                                   unsigned short* __restrict__ xt) {
  const int b = blockIdx.y;
  const int n0 = blockIdx.x * 256;
  __shared__ float tile[DIN * 256];
  const int wave = threadIdx.x >> 6;
  const int lane = threadIdx.x & 63;
#pragma unroll
  for (int d = wave; d < DIN; d += 4) {
    const float4 v =
        *(const float4*)&x[((size_t)b * DIN + d) * NN + n0 + lane * 4];
    *(float4*)&tile[d * 256 + lane * 4] = v;
  }
  __syncthreads();
  const int p = (int)threadIdx.x;
  unsigned short* dst = xt + ((size_t)b * NN + n0 + p) * DIN;
#pragma unroll
  for (int j = 0; j < 8; ++j) {
    ushort8 v;
#pragma unroll
    for (int i = 0; i < 8; ++i) v[i] = f2bf(tile[(8 * j + i) * 256 + p]);
    *(ushort8*)&dst[8 * j] = v;
  }
}

// ---------------------------------------------------------------------------
// K3 (MFMA): per (b, ring, stream) block; wave w owns chan-tiles {w, w+4}
// (32 channels). A-fragments = W rows converted to bf16 in-register, loaded
// ONCE and reused for every point. Per 16-point tile: B-fragments straight
// from global xt (lane reads 16B at [n(lane&15)][quad*8+j] -> exact MFMA B
// layout); 4 waves share point tiles so waves 1-3 hit L1/L2. Tail: slot index
// clamped to count-1 (duplicate last point is identity for max).
__global__ void __launch_bounds__(256) k_compute(
    const unsigned short* __restrict__ xt, const float* __restrict__ W,
    const int* __restrict__ counts, const unsigned short* __restrict__ buckets,
    unsigned int* __restrict__ smax_keys) {
  const int seg = blockIdx.x;
  const int r = blockIdx.y;
  const int b = blockIdx.z;
  const int wave = (int)threadIdx.x >> 6;
  const int lane = (int)threadIdx.x & 63;
  const int quad = lane >> 4;
  const int l16 = lane & 15;
  const int count = counts[b * NR + r];
  if (count == 0) return;
  const unsigned short* bk = buckets + (size_t)(b * NR + r) * NN;
  const unsigned short* xb = xt + (size_t)b * NN * DIN;

  // A fragments: af[tt][kstep], tile t = wave + 4*tt, A[m=l16][k=quad*8+j]
  short8 af[2][2];
#pragma unroll
  for (int tt = 0; tt < 2; ++tt) {
    const int chan = (wave + 4 * tt) * 16 + l16;
    const float* wr = W + ((size_t)r * DOUT + chan) * DIN + quad * 8;
#pragma unroll
    for (int ks = 0; ks < 2; ++ks) {
      const float4 w0 = *(const float4*)&wr[ks * 32];
      const float4 w1 = *(const float4*)&wr[ks * 32 + 4];
      short8 a;
      a[0] = (short)f2bf(w0.x); a[1] = (short)f2bf(w0.y);
      a[2] = (short)f2bf(w0.z); a[3] = (short)f2bf(w0.w);
      a[4] = (short)f2bf(w1.x); a[5] = (short)f2bf(w1.y);
      a[6] = (short)f2bf(w1.z); a[7] = (short)f2bf(w1.w);
      af[tt][ks] = a;
    }
  }

  floatx4 rmax0 = {-INFINITY, -INFINITY, -INFINITY, -INFINITY};
  floatx4 rmax1 = rmax0;

  const int tiles = (count + 15) >> 4;
  for (int T = seg; T < tiles; T += SEGS) {
    int s = T * 16 + l16;
    if (s > count - 1) s = count - 1;
    const int n = bk[s];
    const unsigned short* xr = xb + (size_t)n * DIN + quad * 8;
    const short8 b0 = *(const short8*)&xr[0];
    const short8 b1 = *(const short8*)&xr[32];
    floatx4 acc0 = {0.f, 0.f, 0.f, 0.f};
    floatx4 acc1 = {0.f, 0.f, 0.f, 0.f};
    acc0 = __builtin_amdgcn_mfma_f32_16x16x32_bf16(af[0][0], b0, acc0, 0, 0, 0);
    acc0 = __builtin_amdgcn_mfma_f32_16x16x32_bf16(af[0][1], b1, acc0, 0, 0, 0);
    acc1 = __builtin_amdgcn_mfma_f32_16x16x32_bf16(af[1][0], b0, acc1, 0, 0, 0);
    acc1 = __builtin_amdgcn_mfma_f32_16x16x32_bf16(af[1][1], b1, acc1, 0, 0, 0);
#pragma unroll
    for (int p = 0; p < 4; ++p) {
      rmax0[p] = fmaxf(rmax0[p], acc0[p]);
      rmax1[p] = fmaxf(rmax1[p], acc1[p]);
    }
  }

  // reduce max over the 16 point-columns (lane bits 0-3), then one atomic per
  // (tile, quad, reg) = one per channel.
#pragma unroll
  for (int tt = 0; tt < 2; ++tt) {
#pragma unroll
    for (int p = 0; p < 4; ++p) {
      float v = (tt == 0) ? rmax0[p] : rmax1[p];
      v = fmaxf(v, __shfl_xor(v, 1, 64));
      v = fmaxf(v, __shfl_xor(v, 2, 64));
      v = fmaxf(v, __shfl_xor(v, 4, 64));
      v = fmaxf(v, __shfl_xor(v, 8, 64));
      if (l16 == 0) {
        const int chan = (wave + 4 * tt) * 16 + quad * 4 + p;
        const unsigned int u = __float_as_uint(v);
        const unsigned int key = (u & 0x80000000u) ? ~u : (u | 0x80000000u);
        atomicMax(&smax_keys[(size_t)(b * NR + r) * DOUT + chan], key);
      }
    }
  }
}

// ---------------------------------------------------------------------------
// K4: finalize affine on the 16K maxima, then broadcast to output:
// out[b][o][n] = ymax[b][ring[b,n]][o]. Nontemporal float4 stores along n.
__global__ void k_out(const float* __restrict__ bias, const float* __restrict__ gamma,
                      const float* __restrict__ beta, const float* __restrict__ mean,
                      const float* __restrict__ var, const int* __restrict__ ring,
                      const unsigned int* __restrict__ smax_keys,
                      float* __restrict__ out) {
  const int b = blockIdx.z;
  const int og = blockIdx.y;  // 32-channel group
  const int n0 = blockIdx.x * 1024;

  __shared__ float ymax[32 * NR];  // [oo][r]
  if (threadIdx.x < 32 * NR) {
    const int oo = (int)threadIdx.x >> 2;
    const int r = (int)threadIdx.x & 3;
    const int o = og * 32 + oo;
    const int t = r * DOUT + o;
    const unsigned int key = smax_keys[(size_t)b * NR * DOUT + t];
    const unsigned int u = (key & 0x80000000u) ? (key ^ 0x80000000u) : ~key;
    const float raw = __uint_as_float(u);
    const float sc = gamma[t] * rsqrtf(var[t] + BN_EPS);
    ymax[oo * NR + r] = (raw + bias[t] - mean[t]) * sc + beta[t];
  }
  __syncthreads();

  const int n = n0 + (int)threadIdx.x * 4;
  const int4 rg = *(const int4*)&ring[(size_t)b * NN + n];
#pragma unroll 8
  for (int oo = 0; oo < 32; ++oo) {
    const int o = og * 32 + oo;
    nfloat4 v;
    v.x = ymax[oo * NR + rg.x];
    v.y = ymax[oo * NR + rg.y];
    v.z = ymax[oo * NR + rg.z];
    v.w = ymax[oo * NR + rg.w];
    __builtin_nontemporal_store(v, (nfloat4*)&out[((size_t)b * DOUT + o) * NN + n]);
  }
}

// ---------------------------------------------------------------------------
extern "C" void kernel_launch(void* const* d_in, const int* in_sizes, int n_in,
                              void* d_out, int out_size, void* d_ws, size_t ws_size,
                              hipStream_t stream) {
  const float* x = (const float*)d_in[0];
  const int* ring = (const int*)d_in[1];
  const float* W = (const float*)d_in[2];
  const float* bias = (const float*)d_in[3];
  const float* gamma = (const float*)d_in[4];
  const float* beta = (const float*)d_in[5];
  const float* mean = (const float*)d_in[6];
  const float* var = (const float*)d_in[7];
  float* out = (float*)d_out;

  char* ws = (char*)d_ws;
  int* counts = (int*)(ws + 0);
  unsigned int* keys = (unsigned int*)(ws + WS_KEYS_OFF);
  unsigned short* buckets = (unsigned short*)(ws + WS_BUCKETS_OFF);
  unsigned short* xt = (unsigned short*)d_out;  // 32 MB bf16, consumed pre-k_out

  // zero counts + smax keys (key 0 decodes to -NaN, i.e. identity for max)
  (void)hipMemsetAsync(ws, 0, WS_KEYS_OFF + (size_t)BB * NR * DOUT * 4, stream);

  k_bucket<<<dim3(NN / 1024, BB), 256, 0, stream>>>(ring, counts, buckets);
  k_transpose<<<dim3(NN / 256, BB), 256, 0, stream>>>(x, xt);
  k_compute<<<dim3(SEGS, NR, BB), 256, 0, stream>>>(xt, W, counts, buckets, keys);
  k_out<<<dim3(NN / 1024, DOUT / 32, BB), 256, 0, stream>>>(bias, gamma, beta, mean,
                                                            var, ring, keys, out);
}

// Round 7
// 230.392 us; speedup vs baseline: 9.6217x; 1.1264x over previous
//
#include <hip/hip_runtime.h>
#include <hip/hip_bf16.h>
#include <cstdint>
#include <cstddef>

// Problem constants (fixed by reference)
#define BB 32
#define NN 8192
#define DIN 64
#define DOUT 128
#define NR 4
#define BN_EPS 1e-5f

typedef float nfloat4 __attribute__((ext_vector_type(4)));
typedef float floatx4 __attribute__((ext_vector_type(4)));
typedef short short8 __attribute__((ext_vector_type(8)));

// Workspace: [0, 64KB) uint smax_keys[B*NR*128]
// (memset 0 each launch; key 0 decodes below any real value's key)

__device__ inline unsigned short f2bf(float f) {  // RNE float->bf16 (scalar)
  const unsigned int u = __float_as_uint(f);
  return (unsigned short)((u + 0x7fffu + ((u >> 16) & 1u)) >> 16);
}

__device__ inline void pack2(float a, float b, short8& dst, int idx) {
  // packed f32x2 -> bf16x2 (v_cvt_pk_bf16_f32 on gfx950)
  __hip_bfloat162 h = __float22bfloat162_rn(make_float2(a, b));
  const unsigned int bits = *(unsigned int*)&h;
  dst[idx] = (short)(bits & 0xffffu);
  dst[idx + 1] = (short)(bits >> 16);
}

// ---------------------------------------------------------------------------
// K1 (MFMA, no bucketing): block = (b, 256-point chunk). Wave w owns channel
// tiles {w, w+4} (32 chans). B-fragments load DIRECTLY from x's native [d][n]
// layout: lane(l16,quad) reads x[quad*8+j][n0+T*16+l16] -- each 16-lane group
// covers 16 consecutive n = full 64B lines, so x is fetched exactly once,
// fully coalesced. Per-ring segment max via register masks (ring==r ? v : -inf),
// then 16-point butterfly + one atomicMax per (ring, chan).
__global__ void __launch_bounds__(256) k_compute(
    const float* __restrict__ x, const float* __restrict__ W,
    const int* __restrict__ ring, unsigned int* __restrict__ smax_keys) {
  const int b = blockIdx.y;
  const int n0 = blockIdx.x * 256;
  const int wave = (int)threadIdx.x >> 6;
  const int lane = (int)threadIdx.x & 63;
  const int quad = lane >> 4;
  const int l16 = lane & 15;
  const float* xb = x + (size_t)b * DIN * NN;
  const int* rgb = ring + (size_t)b * NN;

  // A fragments: af[tt][kstep], chan-tile t = wave + 4*tt, A[m=l16][k=quad*8+j]
  short8 af[2][2];
#pragma unroll
  for (int tt = 0; tt < 2; ++tt) {
    const int chan = (wave + 4 * tt) * 16 + l16;
    const float* wr = W + ((size_t)blockIdx.z * 0 + 0);  // placeholder, fixed below
    (void)wr;
  }
  // (W is ring-dependent: load all NR rings' A-fragments once -- 4 rings *
  //  2 tiles * 2 ksteps * 4 VGPR = 64 VGPR... too much; instead keep W in
  //  f32 and re-pack per ring? No: we accumulate raw dots for ALL rings at
  //  once -- W must be applied per ring. Trick: the dot uses W[ring[n]]?
  //  NO -- reference applies W[i] to every point, masked by ring==i. But the
  //  output only keeps y where ring==i, so each point only ever contributes
  //  through W[ring[n]]. So the GEMM needs, for point n, the weight matrix
  //  of ITS OWN ring. A single MFMA tile mixes points of different rings,
  //  but A is shared across the tile -- so we must run the tile once per
  //  ring's W anyway? That would 4x the MFMA. Alternative used here: run
  //  4 MFMA passes, one per ring, but SKIP passes where no point in the
  //  tile has that ring (ballot check) -- expected passes per tile ~= 4
  //  only when mixed; for random rings 16 points nearly always hit all 4.
  //  => accept 4x MFMA: still only ~8 us of MFMA. See loop below.)

  floatx4 rmax[2][NR];
#pragma unroll
  for (int tt = 0; tt < 2; ++tt)
#pragma unroll
    for (int r = 0; r < NR; ++r) rmax[tt][r] = {-INFINITY, -INFINITY, -INFINITY, -INFINITY};

  // Pre-load A fragments for all 4 rings (4 rings x 2 tiles x 2 ksteps x 4
  // VGPR = 64 VGPR of bf16 A data). VGPR heavy but fits (~130 total).
  short8 afr[NR][2][2];
#pragma unroll
  for (int r = 0; r < NR; ++r) {
#pragma unroll
    for (int tt = 0; tt < 2; ++tt) {
      const int chan = (wave + 4 * tt) * 16 + l16;
      const float* wr = W + ((size_t)r * DOUT + chan) * DIN + quad * 8;
#pragma unroll
      for (int ks = 0; ks < 2; ++ks) {
        const float4 w0 = *(const float4*)&wr[ks * 32];
        const float4 w1 = *(const float4*)&wr[ks * 32 + 4];
        short8 a;
        pack2(w0.x, w0.y, a, 0);
        pack2(w0.z, w0.w, a, 2);
        pack2(w1.x, w1.y, a, 4);
        pack2(w1.z, w1.w, a, 6);
        afr[r][tt][ks] = a;
      }
    }
  }

#pragma unroll 1
  for (int T = 0; T < 16; ++T) {
    const int n = n0 + T * 16 + l16;
    const int rr = rgb[n];
    // B fragments from native layout: b0 k=quad*8+j, b1 k=32+quad*8+j
    float bx[8], by[8];
#pragma unroll
    for (int j = 0; j < 8; ++j) {
      bx[j] = xb[(size_t)(quad * 8 + j) * NN + n];
      by[j] = xb[(size_t)(32 + quad * 8 + j) * NN + n];
    }
    short8 b0, b1;
#pragma unroll
    for (int j = 0; j < 4; ++j) {
      pack2(bx[2 * j], bx[2 * j + 1], b0, 2 * j);
      pack2(by[2 * j], by[2 * j + 1], b1, 2 * j);
    }
#pragma unroll
    for (int r = 0; r < NR; ++r) {
      floatx4 acc0 = {0.f, 0.f, 0.f, 0.f};
      floatx4 acc1 = {0.f, 0.f, 0.f, 0.f};
      acc0 = __builtin_amdgcn_mfma_f32_16x16x32_bf16(afr[r][0][0], b0, acc0, 0, 0, 0);
      acc0 = __builtin_amdgcn_mfma_f32_16x16x32_bf16(afr[r][0][1], b1, acc0, 0, 0, 0);
      acc1 = __builtin_amdgcn_mfma_f32_16x16x32_bf16(afr[r][1][0], b0, acc1, 0, 0, 0);
      acc1 = __builtin_amdgcn_mfma_f32_16x16x32_bf16(afr[r][1][1], b1, acc1, 0, 0, 0);
      const bool m = (rr == r);
#pragma unroll
      for (int p = 0; p < 4; ++p) {
        rmax[0][r][p] = fmaxf(rmax[0][r][p], m ? acc0[p] : -INFINITY);
        rmax[1][r][p] = fmaxf(rmax[1][r][p], m ? acc1[p] : -INFINITY);
      }
    }
  }

  // reduce over the 16 point-columns (lane bits 0-3); one atomic per
  // (ring, chan) from the l16==0 lane of each quad.
#pragma unroll
  for (int tt = 0; tt < 2; ++tt) {
#pragma unroll
    for (int r = 0; r < NR; ++r) {
#pragma unroll
      for (int p = 0; p < 4; ++p) {
        float v = rmax[tt][r][p];
        v = fmaxf(v, __shfl_xor(v, 1, 64));
        v = fmaxf(v, __shfl_xor(v, 2, 64));
        v = fmaxf(v, __shfl_xor(v, 4, 64));
        v = fmaxf(v, __shfl_xor(v, 8, 64));
        if (l16 == 0) {
          const int chan = (wave + 4 * tt) * 16 + quad * 4 + p;
          const unsigned int u = __float_as_uint(v);
          const unsigned int key = (u & 0x80000000u) ? ~u : (u | 0x80000000u);
          atomicMax(&smax_keys[(size_t)(b * NR + r) * DOUT + chan], key);
        }
      }
    }
  }
}

// ---------------------------------------------------------------------------
// K2: finalize affine on the 16K maxima, then broadcast to output:
// out[b][o][n] = ymax[b][ring[b,n]][o]. Nontemporal float4 stores along n.
__global__ void k_out(const float* __restrict__ bias, const float* __restrict__ gamma,
                      const float* __restrict__ beta, const float* __restrict__ mean,
                      const float* __restrict__ var, const int* __restrict__ ring,
                      const unsigned int* __restrict__ smax_keys,
                      float* __restrict__ out) {
  const int b = blockIdx.z;
  const int og = blockIdx.y;  // 32-channel group
  const int n0 = blockIdx.x * 1024;

  __shared__ float ymax[32 * NR];  // [oo][r]
  if (threadIdx.x < 32 * NR) {
    const int oo = (int)threadIdx.x >> 2;
    const int r = (int)threadIdx.x & 3;
    const int o = og * 32 + oo;
    const int t = r * DOUT + o;
    const unsigned int key = smax_keys[(size_t)b * NR * DOUT + t];
    const unsigned int u = (key & 0x80000000u) ? (key ^ 0x80000000u) : ~key;
    const float raw = __uint_as_float(u);
    const float sc = gamma[t] * rsqrtf(var[t] + BN_EPS);
    ymax[oo * NR + r] = (raw + bias[t] - mean[t]) * sc + beta[t];
  }
  __syncthreads();

  const int n = n0 + (int)threadIdx.x * 4;
  const int4 rg = *(const int4*)&ring[(size_t)b * NN + n];
#pragma unroll 8
  for (int oo = 0; oo < 32; ++oo) {
    const int o = og * 32 + oo;
    nfloat4 v;
    v.x = ymax[oo * NR + rg.x];
    v.y = ymax[oo * NR + rg.y];
    v.z = ymax[oo * NR + rg.z];
    v.w = ymax[oo * NR + rg.w];
    __builtin_nontemporal_store(v, (nfloat4*)&out[((size_t)b * DOUT + o) * NN + n]);
  }
}

// ---------------------------------------------------------------------------
extern "C" void kernel_launch(void* const* d_in, const int* in_sizes, int n_in,
                              void* d_out, int out_size, void* d_ws, size_t ws_size,
                              hipStream_t stream) {
  const float* x = (const float*)d_in[0];
  const int* ring = (const int*)d_in[1];
  const float* W = (const float*)d_in[2];
  const float* bias = (const float*)d_in[3];
  const float* gamma = (const float*)d_in[4];
  const float* beta = (const float*)d_in[5];
  const float* mean = (const float*)d_in[6];
  const float* var = (const float*)d_in[7];
  float* out = (float*)d_out;

  unsigned int* keys = (unsigned int*)d_ws;

  // zero smax keys (key 0 decodes below every real key)
  (void)hipMemsetAsync(keys, 0, (size_t)BB * NR * DOUT * 4, stream);

  k_compute<<<dim3(NN / 256, BB), 256, 0, stream>>>(x, W, ring, keys);
  k_out<<<dim3(NN / 1024, DOUT / 32, BB), 256, 0, stream>>>(bias, gamma, beta, mean,
                                                            var, ring, keys, out);
}